// Round 1
// baseline (144.688 us; speedup 1.0000x reference)
//
#include <hip/hip_runtime.h>

// ESRNN Holt-Winters cell, B=65536 series, T=512 steps, seasonal period M=12.
// One thread per series. 12-step unrolled chunks so the seasonal ring buffer
// has compile-time indices (stays in VGPRs) and x loads are 3x float4/chunk,
// software-prefetched one chunk ahead.

#define STEPM(XV, SH, SN, OV)                                              \
    do {                                                                   \
        const float s_h_ = ring[SH];                                       \
        const float q_   = (XV) * __builtin_amdgcn_rcpf(s_h_);             \
        const float lb_  = fmaf(b, phi, l);                                \
        const float ln_  = fmaf(alpha, q_, omal * lb_);                    \
        const float bphi_ = b * phi;                                       \
        const float bn_  = fmaf(beta, ln_ - l, ombe * bphi_);              \
        const float lb2_ = fmaf(bn_, phi, ln_);                            \
        const float sn_  = fmaf(gamma, (XV) * __builtin_amdgcn_rcpf(lb2_), \
                                omg * s_h_);                               \
        (OV) = lb2_ * ring[SN];                                            \
        ring[SH] = sn_;                                                    \
        l = ln_; b = bn_;                                                  \
    } while (0)

__global__ __launch_bounds__(256) void esrnn_kernel(
    const float* __restrict__ x,
    const float* __restrict__ p_alpha,
    const float* __restrict__ p_beta,
    const float* __restrict__ p_phi,
    const float* __restrict__ p_gamma,
    const float* __restrict__ l0,
    const float* __restrict__ b0,
    const float* __restrict__ s0,
    float* __restrict__ out,
    int B)
{
    constexpr int T = 512;
    const int i = blockIdx.x * blockDim.x + threadIdx.x;
    if (i >= B) return;

    const float alpha = p_alpha[0];
    const float beta  = p_beta[0];
    const float phi   = p_phi[0];
    const float gamma = p_gamma[0];
    const float omal  = 1.0f - alpha;
    const float ombe  = 1.0f - beta;
    const float omg   = 1.0f - gamma;

    float l = l0[i];
    float b = b0[i];

    // seasonal ring: ring[j] holds the s-value consumed at step t with t%12==j
    float ring[12];
    {
        const float4* s04 = reinterpret_cast<const float4*>(s0 + (size_t)i * 12);
        float4 sa = s04[0], sb = s04[1], sc = s04[2];
        ring[0] = sa.x; ring[1] = sa.y; ring[2]  = sa.z; ring[3]  = sa.w;
        ring[4] = sb.x; ring[5] = sb.y; ring[6]  = sb.z; ring[7]  = sb.w;
        ring[8] = sc.x; ring[9] = sc.y; ring[10] = sc.z; ring[11] = sc.w;
    }

    const float4* x4 = reinterpret_cast<const float4*>(x + (size_t)i * T);
    float4*       o4 = reinterpret_cast<float4*>(out + (size_t)i * T);

    // prefetch chunk 0 (steps 0..11)
    float4 xa = x4[0], xb = x4[1], xc = x4[2];

    // 42 full chunks of 12 steps = 504 steps
    #pragma unroll 1
    for (int c = 0; c < 42; ++c) {
        float4 na, nb, nc;
        if (c < 41) {                      // prefetch next 12-step chunk
            na = x4[3 * c + 3];
            nb = x4[3 * c + 4];
            nc = x4[3 * c + 5];
        } else {                           // prefetch the 8-step tail
            na = x4[126];
            nb = x4[127];
            nc = nb;                       // unused
        }

        float4 oa, ob, oc;
        STEPM(xa.x, 0, 1, oa.x);  STEPM(xa.y, 1, 2, oa.y);
        STEPM(xa.z, 2, 3, oa.z);  STEPM(xa.w, 3, 4, oa.w);
        STEPM(xb.x, 4, 5, ob.x);  STEPM(xb.y, 5, 6, ob.y);
        STEPM(xb.z, 6, 7, ob.z);  STEPM(xb.w, 7, 8, ob.w);
        STEPM(xc.x, 8, 9, oc.x);  STEPM(xc.y, 9, 10, oc.y);
        STEPM(xc.z, 10, 11, oc.z); STEPM(xc.w, 11, 0, oc.w);

        o4[3 * c + 0] = oa;
        o4[3 * c + 1] = ob;
        o4[3 * c + 2] = oc;

        xa = na; xb = nb; xc = nc;
    }

    // tail: steps 504..511, (504 % 12) == 0 so ring phase restarts at 0
    {
        float4 oa, ob;
        STEPM(xa.x, 0, 1, oa.x);  STEPM(xa.y, 1, 2, oa.y);
        STEPM(xa.z, 2, 3, oa.z);  STEPM(xa.w, 3, 4, oa.w);
        STEPM(xb.x, 4, 5, ob.x);  STEPM(xb.y, 5, 6, ob.y);
        STEPM(xb.z, 6, 7, ob.z);  STEPM(xb.w, 7, 8, ob.w);
        o4[126] = oa;
        o4[127] = ob;
    }
}

extern "C" void kernel_launch(void* const* d_in, const int* in_sizes, int n_in,
                              void* d_out, int out_size, void* d_ws, size_t ws_size,
                              hipStream_t stream)
{
    const float* x       = (const float*)d_in[0];
    const float* p_alpha = (const float*)d_in[1];
    const float* p_beta  = (const float*)d_in[2];
    const float* p_phi   = (const float*)d_in[3];
    const float* p_gamma = (const float*)d_in[4];
    const float* l0      = (const float*)d_in[5];
    const float* b0      = (const float*)d_in[6];
    const float* s0      = (const float*)d_in[7];
    float* out = (float*)d_out;

    const int B = in_sizes[5];             // l0 has B elements
    const int block = 256;
    const int grid = (B + block - 1) / block;

    esrnn_kernel<<<grid, block, 0, stream>>>(x, p_alpha, p_beta, p_phi, p_gamma,
                                             l0, b0, s0, out, B);
}

// Round 2
// 59.521 us; speedup vs baseline: 2.4309x; 2.4309x over previous
//
#include <hip/hip_runtime.h>

// ESRNN Holt-Winters, B=65536 series, T=512, period M=12.
// One wave (64 threads) per block, 64 series per block, one thread per series.
// Time tiled in 48-step chunks (48 % 12 == 0 -> seasonal ring indices are
// compile-time). Coalesced global <-> LDS transpose so every HBM transaction
// is a full contiguous segment (kills the 2x read+write amplification seen
// with per-thread row streaming). x-LDS double-buffered; global loads for
// chunk k+1 issued before compute of chunk k.

constexpr int TT   = 512;   // timesteps
constexpr int TC   = 48;    // main chunk steps
constexpr int NCH  = 10;    // full chunks (480 steps)
constexpr int SW   = 64;    // series per block (one wave)
constexpr int LST  = 65;    // LDS row stride (padded)
constexpr int PITCH4 = TT / 4;  // row pitch in float4 units (128)

#define STEPM(XV, SH, SN, OV)                                              \
    do {                                                                   \
        const float s_h_ = ring[SH];                                       \
        const float q_   = (XV) * __builtin_amdgcn_rcpf(s_h_);             \
        const float lb_  = fmaf(b, phi, l);                                \
        const float ln_  = fmaf(alpha, q_, omal * lb_);                    \
        const float bphi_ = b * phi;                                       \
        const float bn_  = fmaf(beta, ln_ - l, ombe * bphi_);              \
        const float lb2_ = fmaf(bn_, phi, ln_);                            \
        const float sn_  = fmaf(gamma, (XV) * __builtin_amdgcn_rcpf(lb2_), \
                                omg * s_h_);                               \
        (OV) = lb2_ * ring[SN];                                            \
        ring[SH] = sn_;                                                    \
        l = ln_; b = bn_;                                                  \
    } while (0)

__global__ __launch_bounds__(64) void esrnn_kernel(
    const float* __restrict__ x,
    const float* __restrict__ p_alpha,
    const float* __restrict__ p_beta,
    const float* __restrict__ p_phi,
    const float* __restrict__ p_gamma,
    const float* __restrict__ l0,
    const float* __restrict__ b0,
    const float* __restrict__ s0,
    float* __restrict__ out)
{
    const int tid = threadIdx.x;
    const int blk = blockIdx.x;
    const int series0 = blk * SW;
    const int i = series0 + tid;

    __shared__ float lds_x[2][TC * LST];
    __shared__ float lds_o[TC * LST];

    const float alpha = p_alpha[0];
    const float beta  = p_beta[0];
    const float phi   = p_phi[0];
    const float gamma = p_gamma[0];
    const float omal  = 1.0f - alpha;
    const float ombe  = 1.0f - beta;
    const float omg   = 1.0f - gamma;

    float l = l0[i];
    float b = b0[i];

    float ring[12];
    {
        const float4* s04 = reinterpret_cast<const float4*>(s0 + (size_t)i * 12);
        float4 sa = s04[0], sb = s04[1], sc = s04[2];
        ring[0] = sa.x; ring[1] = sa.y; ring[2]  = sa.z; ring[3]  = sa.w;
        ring[4] = sb.x; ring[5] = sb.y; ring[6]  = sb.z; ring[7]  = sb.w;
        ring[8] = sc.x; ring[9] = sc.y; ring[10] = sc.z; ring[11] = sc.w;
    }

    // per-thread tile mapping, main chunks: flat f4 index f = tid + 64*m,
    // tile is 64 rows x 12 f4-cols  -> row r = f/12, col q = f%12
    int rr[12], qq[12];
    #pragma unroll
    for (int m = 0; m < 12; ++m) {
        const int f = tid + SW * m;
        rr[m] = f / 12;
        qq[m] = f - 12 * rr[m];
    }
    // tail mapping: 64 rows x 8 f4-cols -> r = f>>3, q = f&7
    int rt[8], qt[8];
    #pragma unroll
    for (int m = 0; m < 8; ++m) {
        const int f = tid + SW * m;
        rt[m] = f >> 3;
        qt[m] = f & 7;
    }

    const float4* x4 = reinterpret_cast<const float4*>(x) + (size_t)series0 * PITCH4;
    float4*       o4 = reinterpret_cast<float4*>(out)     + (size_t)series0 * PITCH4;

    float4 vx[12], vn[12];

    // prefetch chunk 0
    #pragma unroll
    for (int m = 0; m < 12; ++m)
        vx[m] = x4[(size_t)rr[m] * PITCH4 + qq[m]];

    #pragma unroll 1
    for (int k = 0; k < NCH; ++k) {
        float* lx = lds_x[k & 1];

        // 1. stage chunk k into LDS (transposed [step][series])
        #pragma unroll
        for (int m = 0; m < 12; ++m) {
            const int cb = qq[m] * 4;
            lx[(cb + 0) * LST + rr[m]] = vx[m].x;
            lx[(cb + 1) * LST + rr[m]] = vx[m].y;
            lx[(cb + 2) * LST + rr[m]] = vx[m].z;
            lx[(cb + 3) * LST + rr[m]] = vx[m].w;
        }

        // 2. issue global loads for chunk k+1 (or the 32-step tail)
        if (k < NCH - 1) {
            #pragma unroll
            for (int m = 0; m < 12; ++m)
                vn[m] = x4[(size_t)rr[m] * PITCH4 + (k + 1) * 12 + qq[m]];
        } else {
            #pragma unroll
            for (int m = 0; m < 8; ++m)
                vn[m] = x4[(size_t)rt[m] * PITCH4 + 120 + qt[m]];
        }

        __syncthreads();

        // 4. compute 48 steps (ring phase is 0 at every chunk start)
        #pragma unroll
        for (int s = 0; s < TC; ++s) {
            const int sh = s % 12;
            const int sn2 = (s + 1) % 12;
            const float xv = lx[s * LST + tid];
            float ov;
            STEPM(xv, sh, sn2, ov);
            lds_o[s * LST + tid] = ov;
        }

        __syncthreads();

        // 6. coalesced store of chunk k outputs
        #pragma unroll
        for (int m = 0; m < 12; ++m) {
            const int cb = qq[m] * 4;
            float4 o;
            o.x = lds_o[(cb + 0) * LST + rr[m]];
            o.y = lds_o[(cb + 1) * LST + rr[m]];
            o.z = lds_o[(cb + 2) * LST + rr[m]];
            o.w = lds_o[(cb + 3) * LST + rr[m]];
            o4[(size_t)rr[m] * PITCH4 + k * 12 + qq[m]] = o;
        }

        #pragma unroll
        for (int m = 0; m < 12; ++m) vx[m] = vn[m];
    }

    // ---- tail: steps 480..511 (32 steps, phase 480%12 == 0) ----
    {
        float* lx = lds_x[0];
        #pragma unroll
        for (int m = 0; m < 8; ++m) {
            const int cb = qt[m] * 4;
            lx[(cb + 0) * LST + rt[m]] = vx[m].x;
            lx[(cb + 1) * LST + rt[m]] = vx[m].y;
            lx[(cb + 2) * LST + rt[m]] = vx[m].z;
            lx[(cb + 3) * LST + rt[m]] = vx[m].w;
        }
        __syncthreads();
        #pragma unroll
        for (int s = 0; s < 32; ++s) {
            const int sh = s % 12;
            const int sn2 = (s + 1) % 12;
            const float xv = lx[s * LST + tid];
            float ov;
            STEPM(xv, sh, sn2, ov);
            lds_o[s * LST + tid] = ov;
        }
        __syncthreads();
        #pragma unroll
        for (int m = 0; m < 8; ++m) {
            const int cb = qt[m] * 4;
            float4 o;
            o.x = lds_o[(cb + 0) * LST + rt[m]];
            o.y = lds_o[(cb + 1) * LST + rt[m]];
            o.z = lds_o[(cb + 2) * LST + rt[m]];
            o.w = lds_o[(cb + 3) * LST + rt[m]];
            o4[(size_t)rt[m] * PITCH4 + 120 + qt[m]] = o;
        }
    }
}

extern "C" void kernel_launch(void* const* d_in, const int* in_sizes, int n_in,
                              void* d_out, int out_size, void* d_ws, size_t ws_size,
                              hipStream_t stream)
{
    const float* x       = (const float*)d_in[0];
    const float* p_alpha = (const float*)d_in[1];
    const float* p_beta  = (const float*)d_in[2];
    const float* p_phi   = (const float*)d_in[3];
    const float* p_gamma = (const float*)d_in[4];
    const float* l0      = (const float*)d_in[5];
    const float* b0      = (const float*)d_in[6];
    const float* s0      = (const float*)d_in[7];
    float* out = (float*)d_out;

    const int B = in_sizes[5];          // l0 has B elements
    const int grid = B / SW;            // 1024 blocks of 64 threads

    esrnn_kernel<<<grid, SW, 0, stream>>>(x, p_alpha, p_beta, p_phi, p_gamma,
                                          l0, b0, s0, out);
}

// Round 3
// 56.476 us; speedup vs baseline: 2.5619x; 1.0539x over previous
//
#include <hip/hip_runtime.h>

// ESRNN Holt-Winters, B=65536 series, T=512, period M=12.
// One wave (64 threads) per block, one thread per series, 48-step time chunks
// (48 % 12 == 0 -> compile-time seasonal ring indices).
// Key change vs R2: NO __syncthreads (single-wave blocks) -> no vmcnt(0)
// barrier drain. LDS producer/consumer ordering via same-wave in-order DS
// pipe + explicit `s_waitcnt lgkmcnt(0)` fences. Prefetch loads for chunk
// k+1 stay in flight across the whole compute of chunk k (fine-grained
// per-register vmcnt waits only at staging).

constexpr int TT     = 512;     // timesteps
constexpr int TC     = 48;      // chunk steps
constexpr int NCH    = 10;      // full chunks (480 steps)
constexpr int SW     = 64;      // series per block (one wave)
constexpr int LST    = 65;      // LDS row stride (padded)
constexpr int PITCH4 = TT / 4;  // row pitch in float4 units (128)

#define LDS_FENCE() asm volatile("s_waitcnt lgkmcnt(0)" ::: "memory")

#define STEPM(XV, SH, SN, OV)                                              \
    do {                                                                   \
        const float s_h_ = ring[SH];                                       \
        const float q_   = (XV) * __builtin_amdgcn_rcpf(s_h_);             \
        const float lb_  = fmaf(b, phi, l);                                \
        const float ln_  = fmaf(alpha, q_, omal * lb_);                    \
        const float bphi_ = b * phi;                                       \
        const float bn_  = fmaf(beta, ln_ - l, ombe * bphi_);              \
        const float lb2_ = fmaf(bn_, phi, ln_);                            \
        const float sn_  = fmaf(gamma, (XV) * __builtin_amdgcn_rcpf(lb2_), \
                                omg * s_h_);                               \
        (OV) = lb2_ * ring[SN];                                            \
        ring[SH] = sn_;                                                    \
        l = ln_; b = bn_;                                                  \
    } while (0)

__global__ __launch_bounds__(64) void esrnn_kernel(
    const float* __restrict__ x,
    const float* __restrict__ p_alpha,
    const float* __restrict__ p_beta,
    const float* __restrict__ p_phi,
    const float* __restrict__ p_gamma,
    const float* __restrict__ l0,
    const float* __restrict__ b0,
    const float* __restrict__ s0,
    float* __restrict__ out)
{
    const int tid = threadIdx.x;
    const int series0 = blockIdx.x * SW;
    const int i = series0 + tid;

    __shared__ float lds_x[TC * LST];   // single buffer (in-order DS makes it safe)
    __shared__ float lds_o[TC * LST];

    const float alpha = p_alpha[0];
    const float beta  = p_beta[0];
    const float phi   = p_phi[0];
    const float gamma = p_gamma[0];
    const float omal  = 1.0f - alpha;
    const float ombe  = 1.0f - beta;
    const float omg   = 1.0f - gamma;

    float l = l0[i];
    float b = b0[i];

    float ring[12];
    {
        const float4* s04 = reinterpret_cast<const float4*>(s0 + (size_t)i * 12);
        float4 sa = s04[0], sb = s04[1], sc = s04[2];
        ring[0] = sa.x; ring[1] = sa.y; ring[2]  = sa.z; ring[3]  = sa.w;
        ring[4] = sb.x; ring[5] = sb.y; ring[6]  = sb.z; ring[7]  = sb.w;
        ring[8] = sc.x; ring[9] = sc.y; ring[10] = sc.z; ring[11] = sc.w;
    }

    // main-chunk tile mapping: flat f4 index f = tid + 64*m over a 64x12 f4
    // tile -> row r = f/12 (series), col q = f%12 (time f4)
    int rr[12], qq[12];
    #pragma unroll
    for (int m = 0; m < 12; ++m) {
        const int f = tid + SW * m;
        rr[m] = f / 12;
        qq[m] = f - 12 * rr[m];
    }
    // tail mapping: 64x8 f4 tile -> r = f>>3, q = f&7
    int rt[8], qt[8];
    #pragma unroll
    for (int m = 0; m < 8; ++m) {
        const int f = tid + SW * m;
        rt[m] = f >> 3;
        qt[m] = f & 7;
    }

    const float4* x4 = reinterpret_cast<const float4*>(x) + (size_t)series0 * PITCH4;
    float4*       o4 = reinterpret_cast<float4*>(out)     + (size_t)series0 * PITCH4;

    float4 vx[12], vn[12];

    // prefetch chunk 0
    #pragma unroll
    for (int m = 0; m < 12; ++m)
        vx[m] = x4[(size_t)rr[m] * PITCH4 + qq[m]];

    #pragma unroll 1
    for (int k = 0; k < NCH; ++k) {
        // 1. stage chunk k into LDS [step][series]; fine-grained vmcnt waits
        //    on vx registers only.
        #pragma unroll
        for (int m = 0; m < 12; ++m) {
            const int cb = qq[m] * 4;
            lds_x[(cb + 0) * LST + rr[m]] = vx[m].x;
            lds_x[(cb + 1) * LST + rr[m]] = vx[m].y;
            lds_x[(cb + 2) * LST + rr[m]] = vx[m].z;
            lds_x[(cb + 3) * LST + rr[m]] = vx[m].w;
        }

        // 2. issue global loads for chunk k+1 (or the 32-step tail) — these
        //    stay in flight across the whole compute phase (no vmcnt drain).
        if (k < NCH - 1) {
            #pragma unroll
            for (int m = 0; m < 12; ++m)
                vn[m] = x4[(size_t)rr[m] * PITCH4 + (k + 1) * 12 + qq[m]];
        } else {
            #pragma unroll
            for (int m = 0; m < 8; ++m)
                vn[m] = x4[(size_t)rt[m] * PITCH4 + 120 + qt[m]];
        }

        LDS_FENCE();   // staging writes visible to compute reads

        // 3. compute 48 steps (ring phase is 0 at every chunk start)
        #pragma unroll
        for (int s = 0; s < TC; ++s) {
            const int sh  = s % 12;
            const int sn2 = (s + 1) % 12;
            const float xv = lds_x[s * LST + tid];
            float ov;
            STEPM(xv, sh, sn2, ov);
            lds_o[s * LST + tid] = ov;
        }

        LDS_FENCE();   // lds_o writes visible to transpose reads

        // 4. coalesced store of chunk k outputs (fire-and-forget)
        #pragma unroll
        for (int m = 0; m < 12; ++m) {
            const int cb = qq[m] * 4;
            float4 o;
            o.x = lds_o[(cb + 0) * LST + rr[m]];
            o.y = lds_o[(cb + 1) * LST + rr[m]];
            o.z = lds_o[(cb + 2) * LST + rr[m]];
            o.w = lds_o[(cb + 3) * LST + rr[m]];
            o4[(size_t)rr[m] * PITCH4 + k * 12 + qq[m]] = o;
        }

        #pragma unroll
        for (int m = 0; m < 12; ++m) vx[m] = vn[m];
    }

    // ---- tail: steps 480..511 (32 steps, phase 480%12 == 0) ----
    {
        #pragma unroll
        for (int m = 0; m < 8; ++m) {
            const int cb = qt[m] * 4;
            lds_x[(cb + 0) * LST + rt[m]] = vx[m].x;
            lds_x[(cb + 1) * LST + rt[m]] = vx[m].y;
            lds_x[(cb + 2) * LST + rt[m]] = vx[m].z;
            lds_x[(cb + 3) * LST + rt[m]] = vx[m].w;
        }
        LDS_FENCE();
        #pragma unroll
        for (int s = 0; s < 32; ++s) {
            const int sh  = s % 12;
            const int sn2 = (s + 1) % 12;
            const float xv = lds_x[s * LST + tid];
            float ov;
            STEPM(xv, sh, sn2, ov);
            lds_o[s * LST + tid] = ov;
        }
        LDS_FENCE();
        #pragma unroll
        for (int m = 0; m < 8; ++m) {
            const int cb = qt[m] * 4;
            float4 o;
            o.x = lds_o[(cb + 0) * LST + rt[m]];
            o.y = lds_o[(cb + 1) * LST + rt[m]];
            o.z = lds_o[(cb + 2) * LST + rt[m]];
            o.w = lds_o[(cb + 3) * LST + rt[m]];
            o4[(size_t)rt[m] * PITCH4 + 120 + qt[m]] = o;
        }
    }
}

extern "C" void kernel_launch(void* const* d_in, const int* in_sizes, int n_in,
                              void* d_out, int out_size, void* d_ws, size_t ws_size,
                              hipStream_t stream)
{
    const float* x       = (const float*)d_in[0];
    const float* p_alpha = (const float*)d_in[1];
    const float* p_beta  = (const float*)d_in[2];
    const float* p_phi   = (const float*)d_in[3];
    const float* p_gamma = (const float*)d_in[4];
    const float* l0      = (const float*)d_in[5];
    const float* b0      = (const float*)d_in[6];
    const float* s0      = (const float*)d_in[7];
    float* out = (float*)d_out;

    const int B = in_sizes[5];          // l0 has B elements
    const int grid = B / SW;            // 1024 blocks of 64 threads

    esrnn_kernel<<<grid, SW, 0, stream>>>(x, p_alpha, p_beta, p_phi, p_gamma,
                                          l0, b0, s0, out);
}

// Round 5
// 47.644 us; speedup vs baseline: 3.0368x; 1.1854x over previous
//
#include <hip/hip_runtime.h>

// ESRNN Holt-Winters, B=65536 series, T=512, period M=12.
// One wave (64 threads) per block, one thread per series, 48-step chunks
// (48 % 12 == 0 -> compile-time seasonal ring indices).
// R5 = R4 with the nontemporal-store compile fix (native vector type).
//  - No s_waitcnt asm fences: same-wave DS pipe is in-order; compiler emits
//    counted lgkmcnt/vmcnt waits. Phase boundaries are zero-instruction
//    compiler barriers so the scheduler can pipeline across phases.
//  - Prefetch depth 2: global x loads issued two chunks ahead.
//  - Non-temporal output stores: keep the out stream from evicting x in L2/L3.

constexpr int TT     = 512;     // timesteps
constexpr int TC     = 48;      // chunk steps
constexpr int NCH    = 10;      // full chunks (480 steps)
constexpr int SW     = 64;      // series per block (one wave)
constexpr int LST    = 65;      // LDS row stride (padded)
constexpr int PITCH4 = TT / 4;  // row pitch in float4 units (128)

typedef float f32x4 __attribute__((ext_vector_type(4)));

#define CBAR() asm volatile("" ::: "memory")   // compiler-only barrier

#define STEPM(XV, SH, SN, OV)                                              \
    do {                                                                   \
        const float s_h_ = ring[SH];                                       \
        const float q_   = (XV) * __builtin_amdgcn_rcpf(s_h_);             \
        const float lb_  = fmaf(b, phi, l);                                \
        const float ln_  = fmaf(alpha, q_, omal * lb_);                    \
        const float bphi_ = b * phi;                                       \
        const float bn_  = fmaf(beta, ln_ - l, ombe * bphi_);              \
        const float lb2_ = fmaf(bn_, phi, ln_);                            \
        const float sn_  = fmaf(gamma, (XV) * __builtin_amdgcn_rcpf(lb2_), \
                                omg * s_h_);                               \
        (OV) = lb2_ * ring[SN];                                            \
        ring[SH] = sn_;                                                    \
        l = ln_; b = bn_;                                                  \
    } while (0)

__global__ __launch_bounds__(64) void esrnn_kernel(
    const float* __restrict__ x,
    const float* __restrict__ p_alpha,
    const float* __restrict__ p_beta,
    const float* __restrict__ p_phi,
    const float* __restrict__ p_gamma,
    const float* __restrict__ l0,
    const float* __restrict__ b0,
    const float* __restrict__ s0,
    float* __restrict__ out)
{
    const int tid = threadIdx.x;
    const int series0 = blockIdx.x * SW;
    const int i = series0 + tid;

    __shared__ float lds_x[TC * LST];
    __shared__ float lds_o[TC * LST];

    const float alpha = p_alpha[0];
    const float beta  = p_beta[0];
    const float phi   = p_phi[0];
    const float gamma = p_gamma[0];
    const float omal  = 1.0f - alpha;
    const float ombe  = 1.0f - beta;
    const float omg   = 1.0f - gamma;

    float l = l0[i];
    float b = b0[i];

    float ring[12];
    {
        const float4* s04 = reinterpret_cast<const float4*>(s0 + (size_t)i * 12);
        float4 sa = s04[0], sb = s04[1], sc = s04[2];
        ring[0] = sa.x; ring[1] = sa.y; ring[2]  = sa.z; ring[3]  = sa.w;
        ring[4] = sb.x; ring[5] = sb.y; ring[6]  = sb.z; ring[7]  = sb.w;
        ring[8] = sc.x; ring[9] = sc.y; ring[10] = sc.z; ring[11] = sc.w;
    }

    // main-chunk tile mapping: flat f4 index f = tid + 64*m over a 64x12 f4
    // tile -> row r = f/12 (series), col q = f%12 (time f4)
    int rr[12], qq[12];
    #pragma unroll
    for (int m = 0; m < 12; ++m) {
        const int f = tid + SW * m;
        rr[m] = f / 12;
        qq[m] = f - 12 * rr[m];
    }
    // tail mapping: 64x8 f4 tile -> r = f>>3, q = f&7
    int rt[8], qt[8];
    #pragma unroll
    for (int m = 0; m < 8; ++m) {
        const int f = tid + SW * m;
        rt[m] = f >> 3;
        qt[m] = f & 7;
    }

    const float4* x4 = reinterpret_cast<const float4*>(x) + (size_t)series0 * PITCH4;
    f32x4*        o4 = reinterpret_cast<f32x4*>(out)      + (size_t)series0 * PITCH4;

    float4 vx[12], vn[12], vm[12];

    // prologue: prefetch chunks 0 and 1
    #pragma unroll
    for (int m = 0; m < 12; ++m)
        vx[m] = x4[(size_t)rr[m] * PITCH4 + qq[m]];
    #pragma unroll
    for (int m = 0; m < 12; ++m)
        vn[m] = x4[(size_t)rr[m] * PITCH4 + 12 + qq[m]];

    #pragma unroll 1
    for (int k = 0; k < NCH; ++k) {
        // 1. stage chunk k into LDS [step][series] (counted vmcnt waits on vx)
        #pragma unroll
        for (int m = 0; m < 12; ++m) {
            const int cb = qq[m] * 4;
            lds_x[(cb + 0) * LST + rr[m]] = vx[m].x;
            lds_x[(cb + 1) * LST + rr[m]] = vx[m].y;
            lds_x[(cb + 2) * LST + rr[m]] = vx[m].z;
            lds_x[(cb + 3) * LST + rr[m]] = vx[m].w;
        }
        CBAR();

        // 2. issue global loads two chunks ahead
        if (k < NCH - 2) {
            #pragma unroll
            for (int m = 0; m < 12; ++m)
                vm[m] = x4[(size_t)rr[m] * PITCH4 + (k + 2) * 12 + qq[m]];
        } else if (k == NCH - 2) {
            #pragma unroll
            for (int m = 0; m < 8; ++m)
                vm[m] = x4[(size_t)rt[m] * PITCH4 + 120 + qt[m]];
        }
        CBAR();

        // 3. compute 48 steps (ring phase is 0 at every chunk start);
        //    in-order DS pipe + counted waits make the stage->read safe.
        #pragma unroll
        for (int s = 0; s < TC; ++s) {
            const int sh  = s % 12;
            const int sn2 = (s + 1) % 12;
            const float xv = lds_x[s * LST + tid];
            float ov;
            STEPM(xv, sh, sn2, ov);
            lds_o[s * LST + tid] = ov;
        }
        CBAR();

        // 4. transpose-read outputs and store (non-temporal, fire-and-forget)
        #pragma unroll
        for (int m = 0; m < 12; ++m) {
            const int cb = qq[m] * 4;
            f32x4 o;
            o.x = lds_o[(cb + 0) * LST + rr[m]];
            o.y = lds_o[(cb + 1) * LST + rr[m]];
            o.z = lds_o[(cb + 2) * LST + rr[m]];
            o.w = lds_o[(cb + 3) * LST + rr[m]];
            __builtin_nontemporal_store(o, &o4[(size_t)rr[m] * PITCH4 + k * 12 + qq[m]]);
        }
        CBAR();

        // rotate prefetch registers
        #pragma unroll
        for (int m = 0; m < 12; ++m) { vx[m] = vn[m]; vn[m] = vm[m]; }
    }

    // ---- tail: steps 480..511 (32 steps, phase 480%12 == 0) ----
    // tail x values were loaded at k == NCH-2 and rotated into vx
    {
        #pragma unroll
        for (int m = 0; m < 8; ++m) {
            const int cb = qt[m] * 4;
            lds_x[(cb + 0) * LST + rt[m]] = vx[m].x;
            lds_x[(cb + 1) * LST + rt[m]] = vx[m].y;
            lds_x[(cb + 2) * LST + rt[m]] = vx[m].z;
            lds_x[(cb + 3) * LST + rt[m]] = vx[m].w;
        }
        CBAR();
        #pragma unroll
        for (int s = 0; s < 32; ++s) {
            const int sh  = s % 12;
            const int sn2 = (s + 1) % 12;
            const float xv = lds_x[s * LST + tid];
            float ov;
            STEPM(xv, sh, sn2, ov);
            lds_o[s * LST + tid] = ov;
        }
        CBAR();
        #pragma unroll
        for (int m = 0; m < 8; ++m) {
            const int cb = qt[m] * 4;
            f32x4 o;
            o.x = lds_o[(cb + 0) * LST + rt[m]];
            o.y = lds_o[(cb + 1) * LST + rt[m]];
            o.z = lds_o[(cb + 2) * LST + rt[m]];
            o.w = lds_o[(cb + 3) * LST + rt[m]];
            __builtin_nontemporal_store(o, &o4[(size_t)rt[m] * PITCH4 + 120 + qt[m]]);
        }
    }
}

extern "C" void kernel_launch(void* const* d_in, const int* in_sizes, int n_in,
                              void* d_out, int out_size, void* d_ws, size_t ws_size,
                              hipStream_t stream)
{
    const float* x       = (const float*)d_in[0];
    const float* p_alpha = (const float*)d_in[1];
    const float* p_beta  = (const float*)d_in[2];
    const float* p_phi   = (const float*)d_in[3];
    const float* p_gamma = (const float*)d_in[4];
    const float* l0      = (const float*)d_in[5];
    const float* b0      = (const float*)d_in[6];
    const float* s0      = (const float*)d_in[7];
    float* out = (float*)d_out;

    const int B = in_sizes[5];          // l0 has B elements
    const int grid = B / SW;            // 1024 blocks of 64 threads

    esrnn_kernel<<<grid, SW, 0, stream>>>(x, p_alpha, p_beta, p_phi, p_gamma,
                                          l0, b0, s0, out);
}

// Round 6
// 46.615 us; speedup vs baseline: 3.1039x; 1.0221x over previous
//
#include <hip/hip_runtime.h>

// ESRNN Holt-Winters, B=65536 series, T=512, period M=12.
// One wave (64 threads) per block, one thread per series, 48-step chunks
// (48 % 12 == 0 -> compile-time seasonal ring indices).
// R6 changes vs R5: all-b128 LDS. Layout [series][time-f4] with 16B-slot XOR
// swizzle (slot = q ^ (series&7), row stride 64 floats) so staging writes,
// compute reads, output writes and transpose reads are all ds_*_b128 and
// conflict-free. 48 DS ops/chunk instead of 192 b32 (in-order DS pipe is a
// serial per-wave resource at 1 wave/SIMD -> DS count is wall time).

constexpr int TT     = 512;     // timesteps
constexpr int TC     = 48;      // chunk steps
constexpr int NCH    = 10;      // full chunks (480 steps)
constexpr int SW     = 64;      // series per block (one wave)
constexpr int SROW   = 64;      // LDS row stride in floats (16 slots of 16B)
constexpr int PITCH4 = TT / 4;  // global row pitch in float4 units (128)

typedef float f32x4 __attribute__((ext_vector_type(4)));

#define CBAR() asm volatile("" ::: "memory")   // compiler-only barrier

#define STEPM(XV, SH, SN, OV)                                              \
    do {                                                                   \
        const float s_h_ = ring[SH];                                       \
        const float q_   = (XV) * __builtin_amdgcn_rcpf(s_h_);             \
        const float lb_  = fmaf(b, phi, l);                                \
        const float ln_  = fmaf(alpha, q_, omal * lb_);                    \
        const float bphi_ = b * phi;                                       \
        const float bn_  = fmaf(beta, ln_ - l, ombe * bphi_);              \
        const float lb2_ = fmaf(bn_, phi, ln_);                            \
        const float sn_  = fmaf(gamma, (XV) * __builtin_amdgcn_rcpf(lb2_), \
                                omg * s_h_);                               \
        (OV) = lb2_ * ring[SN];                                            \
        ring[SH] = sn_;                                                    \
        l = ln_; b = bn_;                                                  \
    } while (0)

__global__ __launch_bounds__(64) void esrnn_kernel(
    const float* __restrict__ x,
    const float* __restrict__ p_alpha,
    const float* __restrict__ p_beta,
    const float* __restrict__ p_phi,
    const float* __restrict__ p_gamma,
    const float* __restrict__ l0,
    const float* __restrict__ b0,
    const float* __restrict__ s0,
    float* __restrict__ out)
{
    const int tid = threadIdx.x;
    const int t7  = tid & 7;
    const int series0 = blockIdx.x * SW;
    const int i = series0 + tid;

    __shared__ __align__(16) float lds_x[SW * SROW];   // 16 KB
    __shared__ __align__(16) float lds_o[SW * SROW];   // 16 KB

    const float alpha = p_alpha[0];
    const float beta  = p_beta[0];
    const float phi   = p_phi[0];
    const float gamma = p_gamma[0];
    const float omal  = 1.0f - alpha;
    const float ombe  = 1.0f - beta;
    const float omg   = 1.0f - gamma;

    float l = l0[i];
    float b = b0[i];

    float ring[12];
    {
        const f32x4* s04 = reinterpret_cast<const f32x4*>(s0 + (size_t)i * 12);
        f32x4 sa = s04[0], sb = s04[1], sc = s04[2];
        ring[0] = sa.x; ring[1] = sa.y; ring[2]  = sa.z; ring[3]  = sa.w;
        ring[4] = sb.x; ring[5] = sb.y; ring[6]  = sb.z; ring[7]  = sb.w;
        ring[8] = sc.x; ring[9] = sc.y; ring[10] = sc.z; ring[11] = sc.w;
    }

    // main-chunk tile mapping: flat f4 index f = tid + 64*m over a 64x12 f4
    // tile -> series row r = f/12, time f4-col q = f%12. Precompute swizzled
    // LDS float offsets: r*SROW + ((q ^ (r&7)) << 2).
    int rr[12], qq[12], lo[12];
    #pragma unroll
    for (int m = 0; m < 12; ++m) {
        const int f = tid + SW * m;
        rr[m] = f / 12;
        qq[m] = f - 12 * rr[m];
        lo[m] = rr[m] * SROW + ((qq[m] ^ (rr[m] & 7)) << 2);
    }
    // tail mapping: 64x8 f4 tile -> r = f>>3, q = f&7
    int rt[8], qt[8], lt[8];
    #pragma unroll
    for (int m = 0; m < 8; ++m) {
        const int f = tid + SW * m;
        rt[m] = f >> 3;
        qt[m] = f & 7;
        lt[m] = rt[m] * SROW + ((qt[m] ^ (rt[m] & 7)) << 2);
    }

    const f32x4* x4 = reinterpret_cast<const f32x4*>(x) + (size_t)series0 * PITCH4;
    f32x4*       o4 = reinterpret_cast<f32x4*>(out)     + (size_t)series0 * PITCH4;

    f32x4 vx[12], vn[12], vm[12];

    // prologue: prefetch chunks 0 and 1
    #pragma unroll
    for (int m = 0; m < 12; ++m)
        vx[m] = x4[(size_t)rr[m] * PITCH4 + qq[m]];
    #pragma unroll
    for (int m = 0; m < 12; ++m)
        vn[m] = x4[(size_t)rr[m] * PITCH4 + 12 + qq[m]];

    #pragma unroll 1
    for (int k = 0; k < NCH; ++k) {
        // 1. stage chunk k into LDS, 12 x ds_write_b128 (counted vmcnt on vx)
        #pragma unroll
        for (int m = 0; m < 12; ++m)
            *reinterpret_cast<f32x4*>(&lds_x[lo[m]]) = vx[m];
        CBAR();

        // 2. issue global loads two chunks ahead
        if (k < NCH - 2) {
            #pragma unroll
            for (int m = 0; m < 12; ++m)
                vm[m] = x4[(size_t)rr[m] * PITCH4 + (k + 2) * 12 + qq[m]];
        } else if (k == NCH - 2) {
            #pragma unroll
            for (int m = 0; m < 8; ++m)
                vm[m] = x4[(size_t)rt[m] * PITCH4 + 120 + qt[m]];
        }
        CBAR();

        // 3. compute 48 steps: 12 x (b128 read, 4 steps, b128 write)
        #pragma unroll
        for (int q = 0; q < 12; ++q) {
            const int sl = tid * SROW + ((q ^ t7) << 2);
            const f32x4 xq = *reinterpret_cast<const f32x4*>(&lds_x[sl]);
            f32x4 oq;
            STEPM(xq.x, (4 * q + 0) % 12, (4 * q + 1) % 12, oq.x);
            STEPM(xq.y, (4 * q + 1) % 12, (4 * q + 2) % 12, oq.y);
            STEPM(xq.z, (4 * q + 2) % 12, (4 * q + 3) % 12, oq.z);
            STEPM(xq.w, (4 * q + 3) % 12, (4 * q + 4) % 12, oq.w);
            *reinterpret_cast<f32x4*>(&lds_o[sl]) = oq;
        }
        CBAR();

        // 4. transpose-read outputs (12 x b128) and non-temporal store
        #pragma unroll
        for (int m = 0; m < 12; ++m) {
            const f32x4 o = *reinterpret_cast<const f32x4*>(&lds_o[lo[m]]);
            __builtin_nontemporal_store(o, &o4[(size_t)rr[m] * PITCH4 + k * 12 + qq[m]]);
        }
        CBAR();

        // rotate prefetch registers
        #pragma unroll
        for (int m = 0; m < 12; ++m) { vx[m] = vn[m]; vn[m] = vm[m]; }
    }

    // ---- tail: steps 480..511 (32 steps, phase 480%12 == 0) ----
    // tail x values were loaded at k == NCH-2 and rotated into vx
    {
        #pragma unroll
        for (int m = 0; m < 8; ++m)
            *reinterpret_cast<f32x4*>(&lds_x[lt[m]]) = vx[m];
        CBAR();
        #pragma unroll
        for (int q = 0; q < 8; ++q) {
            const int sl = tid * SROW + ((q ^ t7) << 2);
            const f32x4 xq = *reinterpret_cast<const f32x4*>(&lds_x[sl]);
            f32x4 oq;
            STEPM(xq.x, (4 * q + 0) % 12, (4 * q + 1) % 12, oq.x);
            STEPM(xq.y, (4 * q + 1) % 12, (4 * q + 2) % 12, oq.y);
            STEPM(xq.z, (4 * q + 2) % 12, (4 * q + 3) % 12, oq.z);
            STEPM(xq.w, (4 * q + 3) % 12, (4 * q + 4) % 12, oq.w);
            *reinterpret_cast<f32x4*>(&lds_o[sl]) = oq;
        }
        CBAR();
        #pragma unroll
        for (int m = 0; m < 8; ++m) {
            const f32x4 o = *reinterpret_cast<const f32x4*>(&lds_o[lt[m]]);
            __builtin_nontemporal_store(o, &o4[(size_t)rt[m] * PITCH4 + 120 + qt[m]]);
        }
    }
}

extern "C" void kernel_launch(void* const* d_in, const int* in_sizes, int n_in,
                              void* d_out, int out_size, void* d_ws, size_t ws_size,
                              hipStream_t stream)
{
    const float* x       = (const float*)d_in[0];
    const float* p_alpha = (const float*)d_in[1];
    const float* p_beta  = (const float*)d_in[2];
    const float* p_phi   = (const float*)d_in[3];
    const float* p_gamma = (const float*)d_in[4];
    const float* l0      = (const float*)d_in[5];
    const float* b0      = (const float*)d_in[6];
    const float* s0      = (const float*)d_in[7];
    float* out = (float*)d_out;

    const int B = in_sizes[5];          // l0 has B elements
    const int grid = B / SW;            // 1024 blocks of 64 threads

    esrnn_kernel<<<grid, SW, 0, stream>>>(x, p_alpha, p_beta, p_phi, p_gamma,
                                          l0, b0, s0, out);
}